// Round 6
// baseline (858.426 us; speedup 1.0000x reference)
//
#include <hip/hip_runtime.h>
#include <hip/hip_bf16.h>
#include <math.h>

#define BB 16
#define CC 128
#define LL 16384
#define SS 128
#define LK 4096
#define NHEAD 8
#define DH 16

typedef __attribute__((ext_vector_type(8))) short short8;
typedef __attribute__((ext_vector_type(4))) float f32x4;

__device__ __forceinline__ float gelu_f(float x) {
    return 0.5f * x * (1.0f + erff(x * 0.70710678118654752f));
}

__device__ __forceinline__ ushort f2bf(float f) {
    __hip_bfloat16 h = __float2bfloat16(f);
    return *(ushort*)&h;
}
__device__ __forceinline__ float bf2f(ushort u) {
    union { unsigned int i; float f; } x; x.i = ((unsigned int)u) << 16; return x.f;
}

// Reduce s1,s2 across the block; result valid in thread 0.
__device__ __forceinline__ void block_reduce2(float& s1, float& s2) {
    #pragma unroll
    for (int off = 32; off; off >>= 1) {
        s1 += __shfl_down(s1, off);
        s2 += __shfl_down(s2, off);
    }
    __shared__ float red[2][4];
    int wid = threadIdx.x >> 6, lid = threadIdx.x & 63;
    if (lid == 0) { red[0][wid] = s1; red[1][wid] = s2; }
    __syncthreads();
    if (threadIdx.x == 0) {
        int nw = blockDim.x >> 6;
        float a = 0.f, b = 0.f;
        for (int i = 0; i < nw; i++) { a += red[0][i]; b += red[1][i]; }
        s1 = a; s2 = b;
    }
}

// ---------------------------------------------------------------------------
// K_dw: depthwise 3x3, all 3 branches, fused per-(branch,channel) stats.
// Block = (b, oh, cg-of-16ch): LDS 3 rows x 16 ch = 24.8KB -> 6 blocks/CU
// (24 waves, was 3 blocks/12 waves: latency-bound fix).
// Thread = one channel (cl = tid>>4) x 8 contiguous ow (owg = tid&15).
// Output layout: dw* = [b][cg8][p][c16].
__global__ __launch_bounds__(256) void k_dw(const float* __restrict__ x,
        const float* __restrict__ dw_w,
        ushort* __restrict__ dwq, ushort* __restrict__ dwk, ushort* __restrict__ dwv,
        float* __restrict__ dwstats) {
    int bx = blockIdx.x;
    int cg = bx & 7;
    int oh = (bx >> 3) & 127;
    int b  = bx >> 10;
    __shared__ float xs[3][16][132];   // 24.8 KB
    int tid = threadIdx.x;
    int cl  = tid >> 4;        // channel-local 0..15
    int owg = tid & 15;
    int ow0 = owg * 8;
    int c   = cg * 16 + cl;
    bool do_kv = ((oh & 1) == 0);

    // weights into registers
    float wq[9], wk[9], wv[9];
    const float* wp = dw_w + (size_t)c * 9;
    #pragma unroll
    for (int t = 0; t < 9; t++) wq[t] = wp[t];
    #pragma unroll
    for (int t = 0; t < 9; t++) wk[t] = wp[(size_t)CC * 9 + t];
    #pragma unroll
    for (int t = 0; t < 9; t++) wv[t] = wp[(size_t)2 * CC * 9 + t];

    // stage 3 input rows (16 ch x 128 floats); zero OOB rows
    for (int i = tid; i < 3 * 16 * 32; i += 256) {
        int r = i >> 9;
        int rem = i & 511;
        int ch = rem >> 5;
        int f4 = rem & 31;
        int ih = oh - 1 + r;
        float4 v = make_float4(0.f, 0.f, 0.f, 0.f);
        if (ih >= 0 && ih < 128)
            v = *(const float4*)(x + ((size_t)b * CC + cg * 16 + ch) * (size_t)LL + ih * SS + f4 * 4);
        *(float4*)&xs[r][ch][f4 * 4] = v;
    }
    // zero pad columns 128..131
    if (tid < 48) {
        int r = tid >> 4, ch = tid & 15;
        *(float4*)&xs[r][ch][128] = make_float4(0.f, 0.f, 0.f, 0.f);
    }
    __syncthreads();

    float aq[8], ak[4], av[4];
    #pragma unroll
    for (int j = 0; j < 8; j++) aq[j] = 0.f;
    #pragma unroll
    for (int j = 0; j < 4; j++) { ak[j] = 0.f; av[j] = 0.f; }

    #pragma unroll
    for (int r = 0; r < 3; r++) {
        const float* row = &xs[r][cl][0];
        float g[10];
        g[0] = owg ? row[ow0 - 1] : 0.f;        // left pad
        float4 v0 = *(const float4*)&row[ow0];
        float4 v1 = *(const float4*)&row[ow0 + 4];
        g[1] = v0.x;  g[2] = v0.y;  g[3] = v0.z;  g[4] = v0.w;
        g[5] = v1.x;  g[6] = v1.y;  g[7] = v1.z;  g[8] = v1.w;
        g[9] = row[ow0 + 8];                    // col 128 zero-padded
        float w0 = wq[3 * r], w1 = wq[3 * r + 1], w2 = wq[3 * r + 2];
        #pragma unroll
        for (int j = 0; j < 8; j++)
            aq[j] += w0 * g[j] + w1 * g[j + 1] + w2 * g[j + 2];
        if (do_kv) {
            float k0 = wk[3 * r], k1 = wk[3 * r + 1], k2 = wk[3 * r + 2];
            float x0 = wv[3 * r], x1 = wv[3 * r + 1], x2 = wv[3 * r + 2];
            #pragma unroll
            for (int j = 0; j < 4; j++) {
                ak[j] += k0 * g[2 * j] + k1 * g[2 * j + 1] + k2 * g[2 * j + 2];
                av[j] += x0 * g[2 * j] + x1 * g[2 * j + 1] + x2 * g[2 * j + 2];
            }
        }
    }

    // q: bf16 store + fused stats (sum of bf16-rounded values)
    {
        size_t qbase = (((size_t)b * 8 + cg) * LL + (size_t)oh * 128) * 16 + cl;
        float s1 = 0.f, s2 = 0.f;
        #pragma unroll
        for (int j = 0; j < 8; j++) {
            ushort u = f2bf(aq[j]);
            float fv = bf2f(u);
            s1 += fv; s2 += fv * fv;
            dwq[qbase + (size_t)(ow0 + j) * 16] = u;
        }
        #pragma unroll
        for (int m = 1; m <= 8; m <<= 1) {
            s1 += __shfl_xor(s1, m);
            s2 += __shfl_xor(s2, m);
        }
        if (owg == 0) {
            atomicAdd(&dwstats[(size_t)c * 2 + 0], s1);
            atomicAdd(&dwstats[(size_t)c * 2 + 1], s2);
        }
    }

    if (do_kv) {
        int ohp = oh >> 1;
        size_t kbase = (((size_t)b * 8 + cg) * LK + (size_t)ohp * 64) * 16 + cl;
        float t1 = 0.f, t2 = 0.f, u1 = 0.f, u2 = 0.f;
        #pragma unroll
        for (int j = 0; j < 4; j++) {
            int owp = owg * 4 + j;
            ushort uk = f2bf(ak[j]);
            float fk = bf2f(uk);
            t1 += fk; t2 += fk * fk;
            dwk[kbase + (size_t)owp * 16] = uk;
            ushort uv = f2bf(av[j]);
            float fv = bf2f(uv);
            u1 += fv; u2 += fv * fv;
            dwv[kbase + (size_t)owp * 16] = uv;
        }
        #pragma unroll
        for (int m = 1; m <= 8; m <<= 1) {
            t1 += __shfl_xor(t1, m); t2 += __shfl_xor(t2, m);
            u1 += __shfl_xor(u1, m); u2 += __shfl_xor(u2, m);
        }
        if (owg == 0) {
            atomicAdd(&dwstats[((size_t)CC + c) * 2 + 0], t1);
            atomicAdd(&dwstats[((size_t)CC + c) * 2 + 1], t2);
            atomicAdd(&dwstats[((size_t)2 * CC + c) * 2 + 0], u1);
            atomicAdd(&dwstats[((size_t)2 * CC + c) * 2 + 1], u2);
        }
    }
}

// ---------------------------------------------------------------------------
// Fold BN2d into pointwise: effWb[br][o][c] bf16, effB[br][o] fp32.
__global__ void k_finalize_dw(const float* __restrict__ stats, const float* __restrict__ pw_w,
                              const float* __restrict__ pw_b, const float* __restrict__ bn2_g,
                              const float* __restrict__ bn2_b,
                              ushort* __restrict__ effWb, float* __restrict__ effB) {
    int br = blockIdx.x >> 7;
    int o  = blockIdx.x & 127;
    int c  = threadIdx.x;
    float N = (br == 0) ? 262144.f : 65536.f;
    float s1 = stats[(br * CC + c) * 2 + 0];
    float s2 = stats[(br * CC + c) * 2 + 1];
    float m = s1 / N;
    float v = s2 / N - m * m;
    float sc = rsqrtf(v + 1e-5f);
    float A  = bn2_g[br * CC + c] * sc;
    float Bc = bn2_b[br * CC + c] - m * A;
    float w  = pw_w[((size_t)br * CC + o) * CC + c];
    effWb[((size_t)br * CC + o) * CC + c] = f2bf(w * A);
    float pb = w * Bc, dummy = 0.f;
    block_reduce2(pb, dummy);
    if (threadIdx.x == 0) effB[br * CC + o] = pw_b[br * CC + o] + pb;
}

// ---------------------------------------------------------------------------
// GEMM for k/v branches. B (effWb) staged in LDS; A fragments direct from
// global ([b][cg8][p][c16] layout: 16B/lane contiguous, wave-coalesced).
// Wave w owns rows w*16 and w*16+64 -> contiguous 64-row phase bands.
__global__ __launch_bounds__(256, 3) void k_gemm_kv(const ushort* __restrict__ dwk,
        const ushort* __restrict__ dwv, const ushort* __restrict__ effWb,
        const float* __restrict__ effB, float* __restrict__ kbuf, float* __restrict__ vbuf) {
    __shared__ __align__(16) char raw[34816];   // Bs [128][136] shorts; Sf [64][132] f32
    short* Bs = (short*)raw;
    float* Sf = (float*)raw;
    int bx = blockIdx.x;
    int brv = bx >> 9;
    int b = (bx >> 5) & 15;
    int p0 = (bx & 31) * 128;
    const ushort* dw = brv ? dwv : dwk;
    const ushort* Wg = effWb + (size_t)(1 + brv) * CC * CC;
    int tid = threadIdx.x;
    for (int i = tid; i < 2048; i += 256) {
        int row = i >> 4; int f4 = i & 15;
        float4 v = *(const float4*)(Wg + (size_t)row * 128 + f4 * 8);
        *(float4*)&Bs[row * 136 + f4 * 8] = v;
    }
    __syncthreads();
    int w = tid >> 6, l = tid & 63;
    int m0 = w * 16;
    int la = l & 15, lb = l >> 4;
    f32x4 acc[2][8];
    #pragma unroll
    for (int i = 0; i < 2; i++)
        #pragma unroll
        for (int j = 0; j < 8; j++) acc[i][j] = (f32x4){0.f, 0.f, 0.f, 0.f};
    #pragma unroll
    for (int kt = 0; kt < 4; kt++) {
        size_t cgrp = (size_t)b * 8 + kt * 2 + (lb >> 1);
        int csub = (lb & 1) * 8;
        short8 a0 = *(const short8*)(dw + (cgrp * LK + p0 + m0 + la) * 16 + csub);
        short8 a1 = *(const short8*)(dw + (cgrp * LK + p0 + m0 + 64 + la) * 16 + csub);
        int kb = kt * 32 + lb * 8;
        #pragma unroll
        for (int nt = 0; nt < 8; nt++) {
            short8 bf = *(const short8*)&Bs[(nt * 16 + la) * 136 + kb];
            acc[0][nt] = __builtin_amdgcn_mfma_f32_16x16x32_bf16(a0, bf, acc[0][nt], 0, 0, 0);
            acc[1][nt] = __builtin_amdgcn_mfma_f32_16x16x32_bf16(a1, bf, acc[1][nt], 0, 0, 0);
        }
    }
    float bias[8];
    #pragma unroll
    for (int nt = 0; nt < 8; nt++) bias[nt] = effB[(1 + brv) * CC + nt * 16 + la];
    float* outb = (brv ? vbuf : kbuf) + ((size_t)b * LK + p0) * CC;
    #pragma unroll
    for (int t = 0; t < 2; t++) {
        __syncthreads();   // t=0: Bs dead; t=1: prior Sf reads done
        #pragma unroll
        for (int nt = 0; nt < 8; nt++)
            #pragma unroll
            for (int i = 0; i < 4; i++) {
                float vv = acc[t][nt][i] + bias[nt];
                Sf[(m0 + lb * 4 + i) * 132 + nt * 16 + la] = gelu_f(vv);
            }
        __syncthreads();
        for (int i = tid; i < 2048; i += 256) {
            int r = i >> 5; int c4 = i & 31;
            *(float4*)(outb + (size_t)(t * 64 + r) * CC + c4 * 4) = *(const float4*)&Sf[r * 132 + c4 * 4];
        }
    }
}

// ---------------------------------------------------------------------------
// kv accumulation (softmax over sequence): unchanged.
__global__ void k_kv_accum(const float* __restrict__ k_buf, const float* __restrict__ v_buf,
                           float* __restrict__ kv_un, float* __restrict__ ssum) {
    int bx = blockIdx.x;
    int b = bx >> 5;
    int h = (bx >> 2) & 7;
    int sl = bx & 3;
    int n0 = sl * 1024;
    __shared__ float kch[64][16];
    __shared__ float vch[64][16];
    int tid = threadIdx.x;
    int d = tid >> 4, e = tid & 15;
    float acc = 0.f, ss = 0.f;
    for (int ch = 0; ch < 16; ch++) {
        int base = n0 + ch * 64;
        {
            int rr = tid >> 2, c4 = (tid & 3) * 4;
            const float* kp = k_buf + ((size_t)b * LK + base + rr) * CC + h * DH + c4;
            const float* vp = v_buf + ((size_t)b * LK + base + rr) * CC + h * DH + c4;
            float4 kf = *(const float4*)kp;
            float4 vf = *(const float4*)vp;
            kch[rr][c4+0] = __expf(kf.x); kch[rr][c4+1] = __expf(kf.y);
            kch[rr][c4+2] = __expf(kf.z); kch[rr][c4+3] = __expf(kf.w);
            vch[rr][c4+0] = vf.x; vch[rr][c4+1] = vf.y;
            vch[rr][c4+2] = vf.z; vch[rr][c4+3] = vf.w;
        }
        __syncthreads();
        #pragma unroll 8
        for (int rr = 0; rr < 64; rr++) {
            float ek = kch[rr][d];
            acc += ek * vch[rr][e];
            ss += ek;
        }
        __syncthreads();
    }
    atomicAdd(&kv_un[(((size_t)b * NHEAD + h) * DH + d) * DH + e], acc);
    if (e == 0) atomicAdd(&ssum[((size_t)b * NHEAD + h) * DH + d], ss);
}

__global__ void k_kv_div(const float* __restrict__ kv_un, const float* __restrict__ ssum,
                         float* __restrict__ kv) {
    int i = blockIdx.x * 256 + threadIdx.x;
    kv[i] = kv_un[i] / ssum[i >> 4];
}

// ---------------------------------------------------------------------------
// GEMM for q branch + gelu + softmax(dh) + attention + residual. grid 2048.
// B staged in LDS, A direct-global (new [b][cg8][p][c16] layout),
// contiguous 2-phase epilogue.
__global__ __launch_bounds__(256, 3) void k_gemm_q(const ushort* __restrict__ dwq,
        const ushort* __restrict__ effWb, const float* __restrict__ effB,
        const float* __restrict__ kvb, const float* __restrict__ add_w,
        const float* __restrict__ x, float* __restrict__ y1) {
    __shared__ __align__(16) char raw[34816];   // Bs [128][136] shorts; Sf [64][133] f32
    short* Bs = (short*)raw;
    float* Sf = (float*)raw;
    __shared__ float kvs[2048];
    int bx = blockIdx.x;
    int b = bx >> 7;
    int p0 = (bx & 127) * 128;
    int tid = threadIdx.x;
    for (int i = tid; i < 512; i += 256)
        *(float4*)&kvs[i * 4] = *(const float4*)(kvb + (size_t)b * 2048 + i * 4);
    for (int i = tid; i < 2048; i += 256) {
        int row = i >> 4; int f4 = i & 15;
        float4 v = *(const float4*)(effWb + (size_t)row * 128 + f4 * 8);
        *(float4*)&Bs[row * 136 + f4 * 8] = v;
    }
    __syncthreads();
    int w = tid >> 6, l = tid & 63;
    int m0 = w * 16;
    int la = l & 15, lb = l >> 4;
    f32x4 acc[2][8];
    #pragma unroll
    for (int i = 0; i < 2; i++)
        #pragma unroll
        for (int j = 0; j < 8; j++) acc[i][j] = (f32x4){0.f, 0.f, 0.f, 0.f};
    #pragma unroll
    for (int kt = 0; kt < 4; kt++) {
        size_t cgrp = (size_t)b * 8 + kt * 2 + (lb >> 1);
        int csub = (lb & 1) * 8;
        short8 a0 = *(const short8*)(dwq + (cgrp * LL + p0 + m0 + la) * 16 + csub);
        short8 a1 = *(const short8*)(dwq + (cgrp * LL + p0 + m0 + 64 + la) * 16 + csub);
        int kb = kt * 32 + lb * 8;
        #pragma unroll
        for (int nt = 0; nt < 8; nt++) {
            short8 bf = *(const short8*)&Bs[(nt * 16 + la) * 136 + kb];
            acc[0][nt] = __builtin_amdgcn_mfma_f32_16x16x32_bf16(a0, bf, acc[0][nt], 0, 0, 0);
            acc[1][nt] = __builtin_amdgcn_mfma_f32_16x16x32_bf16(a1, bf, acc[1][nt], 0, 0, 0);
        }
    }
    float bias[8];
    #pragma unroll
    for (int nt = 0; nt < 8; nt++) bias[nt] = effB[nt * 16 + la];
    float wa0 = add_w[0], wa1 = add_w[1];
    float r0 = fmaxf(wa0, 0.f), r1 = fmaxf(wa1, 0.f);
    float inv = 1.f / (r0 + r1 + 1e-12f);
    float wn0 = r0 * inv, wn1 = r1 * inv;
    #pragma unroll
    for (int t = 0; t < 2; t++) {
        __syncthreads();   // t=0: Bs dead; t=1: prior Sf reads done
        #pragma unroll
        for (int nt = 0; nt < 8; nt++)
            #pragma unroll
            for (int i = 0; i < 4; i++) {
                float vv = acc[t][nt][i] + bias[nt];
                Sf[(m0 + lb * 4 + i) * 133 + nt * 16 + la] = gelu_f(vv);
            }
        __syncthreads();
        // epilogue on the contiguous 64 rows of this phase
        int r64 = tid & 63;
        int hg = tid >> 6;           // wave id -> h wave-uniform (kvs broadcast)
        int pact = t * 64 + r64;
        const float* xb = x + (size_t)b * CC * (size_t)LL + p0 + pact;
        float* yb = y1 + (size_t)b * CC * (size_t)LL + p0 + pact;
        #pragma unroll
        for (int hh = 0; hh < 2; hh++) {
            int h = hg * 2 + hh;
            float sv[16];
            float mx = -1e30f;
            #pragma unroll
            for (int d = 0; d < 16; d++) { sv[d] = Sf[r64 * 133 + h * 16 + d]; mx = fmaxf(mx, sv[d]); }
            float s = 0.f;
            #pragma unroll
            for (int d = 0; d < 16; d++) { sv[d] = __expf(sv[d] - mx); s += sv[d]; }
            float is = 1.f / s;
            #pragma unroll
            for (int e = 0; e < 16; e++) {
                float att = 0.f;
                #pragma unroll
                for (int d = 0; d < 16; d++) att += sv[d] * kvs[(h * 16 + d) * 16 + e];
                int c = h * 16 + e;
                yb[(size_t)c * LL] = wn0 * att * is + wn1 * xb[(size_t)c * LL];
            }
        }
    }
}

// ---------------------------------------------------------------------------
// Per-channel sum/sumsq over [B][C][L]. grid 4096.
__global__ void k_chan_stats(const float* __restrict__ buf, float* __restrict__ stats) {
    int c = blockIdx.x >> 5;
    int s = blockIdx.x & 31;
    int b = s >> 1;
    int p0 = (s & 1) << 13;
    const float* src = buf + (size_t)b * (CC * (size_t)LL) + (size_t)c * LL + p0;
    float s1 = 0.f, s2 = 0.f;
    for (int i = threadIdx.x * 4; i < 8192; i += 1024) {
        float4 v = *(const float4*)(src + i);
        s1 += v.x + v.y + v.z + v.w;
        s2 += v.x * v.x + v.y * v.y + v.z * v.z + v.w * v.w;
    }
    block_reduce2(s1, s2);
    if (threadIdx.x == 0) {
        atomicAdd(&stats[c * 2 + 0], s1);
        atomicAdd(&stats[c * 2 + 1], s2);
    }
}

// ---------------------------------------------------------------------------
__global__ void k_fin1(const float* __restrict__ stats1, const float* __restrict__ bn1_g,
                       const float* __restrict__ bn1_b, const float* __restrict__ W1,
                       const float* __restrict__ b1, const float* __restrict__ W2,
                       float* __restrict__ A1B1, float* __restrict__ effW1,
                       float* __restrict__ effb1, float* __restrict__ W2T) {
    int t = threadIdx.x;
    const float N = 262144.f;
    float m = stats1[t * 2] / N;
    float v = stats1[t * 2 + 1] / N - m * m;
    float sc = rsqrtf(v + 1e-5f);
    float A = bn1_g[t] * sc;
    float Bc = bn1_b[t] - m * A;
    A1B1[t] = A; A1B1[128 + t] = Bc;
    __shared__ float Bs[128];
    Bs[t] = Bc;
    for (int j = 0; j < 32; j++) effW1[t * 32 + j] = W1[t * 32 + j] * A;
    for (int j = 0; j < 32; j++) W2T[t * 32 + j] = W2[j * 128 + t];
    __syncthreads();
    if (t < 32) {
        float s = b1[t];
        for (int c = 0; c < 128; c++) s += W1[c * 32 + t] * Bs[c];
        effb1[t] = s;
    }
}

// ---------------------------------------------------------------------------
// FFN1: f1[b,p,j] = gelu(sum_c effW1[c][j]*y1[b,c,p] + effb1[j]); LDS weights.
__global__ __launch_bounds__(256) void k_ffn1(const float* __restrict__ y1,
        const float* __restrict__ effW1, const float* __restrict__ effb1,
        float* __restrict__ f1) {
    __shared__ float wl[4096];
    __shared__ float bl[32];
    int tid = threadIdx.x;
    for (int i = tid; i < 4096; i += 256) wl[i] = effW1[i];
    if (tid < 32) bl[tid] = effb1[tid];
    __syncthreads();
    int gp = blockIdx.x * 256 + tid;
    int b = gp >> 14, p = gp & 16383;
    const float* col = y1 + (size_t)b * (CC * (size_t)LL) + p;
    float acc[32];
    #pragma unroll
    for (int j = 0; j < 32; j++) acc[j] = bl[j];
    for (int c = 0; c < CC; c++) {
        float v = col[(size_t)c * LL];
        const float4* w4 = (const float4*)&wl[c * 32];
        #pragma unroll
        for (int i = 0; i < 8; i++) {
            float4 w = w4[i];
            acc[4*i+0] += w.x * v; acc[4*i+1] += w.y * v;
            acc[4*i+2] += w.z * v; acc[4*i+3] += w.w * v;
        }
    }
    float4* dst = (float4*)(f1 + (size_t)gp * 32);
    #pragma unroll
    for (int i = 0; i < 8; i++) {
        float4 o4;
        o4.x = gelu_f(acc[4*i+0]); o4.y = gelu_f(acc[4*i+1]);
        o4.z = gelu_f(acc[4*i+2]); o4.w = gelu_f(acc[4*i+3]);
        dst[i] = o4;
    }
}

// ---------------------------------------------------------------------------
// FFN2: f2 = gelu(f1@W2+b2); out = wn0*f2 + wn1*(y1*A1+B1); LDS weights.
__global__ __launch_bounds__(256) void k_ffn2(const float* __restrict__ f1,
        const float* __restrict__ W2T, const float* __restrict__ b2,
        const float* __restrict__ y1, const float* __restrict__ A1B1,
        const float* __restrict__ ffn_add_w, float* __restrict__ outb) {
    __shared__ float wl[4096];
    __shared__ float b2l[128];
    __shared__ float abl[256];
    int tid = threadIdx.x;
    for (int i = tid; i < 4096; i += 256) wl[i] = W2T[i];
    if (tid < 128) b2l[tid] = b2[tid];
    if (tid >= 128) abl[tid - 128] = A1B1[tid - 128];
    if (tid < 128) abl[128 + tid] = A1B1[128 + tid];
    __syncthreads();
    int gp = blockIdx.x * 256 + tid;
    int b = gp >> 14, p = gp & 16383;
    float f[32];
    {
        const float4* src = (const float4*)(f1 + (size_t)gp * 32);
        #pragma unroll
        for (int i = 0; i < 8; i++) {
            float4 v = src[i];
            f[4*i+0] = v.x; f[4*i+1] = v.y; f[4*i+2] = v.z; f[4*i+3] = v.w;
        }
    }
    float wa0 = ffn_add_w[0], wa1 = ffn_add_w[1];
    float r0 = fmaxf(wa0, 0.f), r1 = fmaxf(wa1, 0.f);
    float inv = 1.f / (r0 + r1 + 1e-12f);
    float wn0 = r0 * inv, wn1 = r1 * inv;
    const float* ycol = y1 + (size_t)b * (CC * (size_t)LL) + p;
    float* ocol = outb + (size_t)b * (CC * (size_t)LL) + p;
    for (int c = 0; c < CC; c++) {
        const float4* w4 = (const float4*)&wl[c * 32];
        float a = b2l[c];
        #pragma unroll
        for (int i = 0; i < 8; i++) {
            float4 w = w4[i];
            a += w.x * f[4*i+0] + w.y * f[4*i+1] + w.z * f[4*i+2] + w.w * f[4*i+3];
        }
        float f2 = gelu_f(a);
        float attv = ycol[(size_t)c * LL] * abl[c] + abl[128 + c];
        ocol[(size_t)c * LL] = wn0 * f2 + wn1 * attv;
    }
}

__global__ void k_fin2(const float* __restrict__ stats2, const float* __restrict__ g,
                       const float* __restrict__ bb, float* __restrict__ A2B2) {
    int t = threadIdx.x;
    const float N = 262144.f;
    float m = stats2[t * 2] / N;
    float v = stats2[t * 2 + 1] / N - m * m;
    float sc = rsqrtf(v + 1e-5f);
    float A = g[t] * sc;
    A2B2[t] = A;
    A2B2[128 + t] = bb[t] - m * A;
}

__global__ void k_norm(float* __restrict__ out, const float* __restrict__ A2B2) {
    size_t i = ((size_t)blockIdx.x * 256 + threadIdx.x) * 4;
    int c = (int)((i >> 14) & 127);
    float A = A2B2[c], Bc = A2B2[128 + c];
    float4 v = *(float4*)(out + i);
    v.x = v.x * A + Bc; v.y = v.y * A + Bc; v.z = v.z * A + Bc; v.w = v.w * A + Bc;
    *(float4*)(out + i) = v;
}

// ---------------------------------------------------------------------------
extern "C" void kernel_launch(void* const* d_in, const int* in_sizes, int n_in,
                              void* d_out, int out_size, void* d_ws, size_t ws_size,
                              hipStream_t stream) {
    const float* x        = (const float*)d_in[0];
    const float* dw_w     = (const float*)d_in[1];
    const float* bn2_g    = (const float*)d_in[2];
    const float* bn2_b    = (const float*)d_in[3];
    const float* pw_w     = (const float*)d_in[4];
    const float* pw_b     = (const float*)d_in[5];
    const float* add_w    = (const float*)d_in[6];
    const float* bn1_g    = (const float*)d_in[7];
    const float* bn1_b    = (const float*)d_in[8];
    const float* W1       = (const float*)d_in[9];
    const float* b1       = (const float*)d_in[10];
    const float* W2       = (const float*)d_in[11];
    const float* b2       = (const float*)d_in[12];
    const float* ffn_aw   = (const float*)d_in[13];
    const float* ffn_bn_g = (const float*)d_in[14];
    const float* ffn_bn_b = (const float*)d_in[15];

    float* w = (float*)d_ws;
    size_t off = 0;
    auto alloc = [&](size_t n) { float* p = w + off; off += n; return p; };
    // zero-init accumulator region (contiguous, single memset)
    float* dwstats = alloc(768);
    float* stats1  = alloc(256);
    float* stats2  = alloc(256);
    float* kv_un   = alloc(32768);
    float* ssum    = alloc(2048);
    size_t zero_bytes = off * sizeof(float);
    float* effWb_f = alloc(24576);   // 3*128*128 bf16
    float* effB    = alloc(384);
    float* kvb     = alloc(32768);
    float* A1B1    = alloc(256);
    float* effW1   = alloc(4096);
    float* effb1   = alloc(32);
    float* W2T     = alloc(4096);
    float* A2B2    = alloc(256);
    float* y1      = alloc((size_t)BB * CC * LL);
    float* kbuf    = alloc((size_t)BB * LK * CC);
    float* vbuf    = alloc((size_t)BB * LK * CC);
    float* dwq_f   = alloc((size_t)BB * LL * CC / 2);   // bf16
    float* dwk_f   = alloc((size_t)BB * LK * CC / 2);
    float* dwv_f   = alloc((size_t)BB * LK * CC / 2);
    float* f1      = kbuf;   // alias: kbuf dead after k_kv_accum
    (void)ws_size;

    ushort* effWb = (ushort*)effWb_f;
    ushort* dwq = (ushort*)dwq_f;
    ushort* dwk = (ushort*)dwk_f;
    ushort* dwv = (ushort*)dwv_f;
    float* outf = (float*)d_out;

    hipMemsetAsync(d_ws, 0, zero_bytes, stream);

    k_dw<<<16384, 256, 0, stream>>>(x, dw_w, dwq, dwk, dwv, dwstats);
    k_finalize_dw<<<384, 128, 0, stream>>>(dwstats, pw_w, pw_b, bn2_g, bn2_b, effWb, effB);
    k_gemm_kv<<<1024, 256, 0, stream>>>(dwk, dwv, effWb, effB, kbuf, vbuf);
    k_kv_accum<<<512, 256, 0, stream>>>(kbuf, vbuf, kv_un, ssum);
    k_kv_div<<<128, 256, 0, stream>>>(kv_un, ssum, kvb);
    k_gemm_q<<<2048, 256, 0, stream>>>(dwq, effWb, effB, kvb, add_w, x, y1);
    k_chan_stats<<<4096, 256, 0, stream>>>(y1, stats1);
    k_fin1<<<1, 128, 0, stream>>>(stats1, bn1_g, bn1_b, W1, b1, W2, A1B1, effW1, effb1, W2T);
    k_ffn1<<<1024, 256, 0, stream>>>(y1, effW1, effb1, f1);
    k_ffn2<<<1024, 256, 0, stream>>>(f1, W2T, b2, y1, A1B1, ffn_aw, outf);
    k_chan_stats<<<4096, 256, 0, stream>>>(outf, stats2);
    k_fin2<<<1, 128, 0, stream>>>(stats2, ffn_bn_g, ffn_bn_b, A2B2);
    k_norm<<<32768, 256, 0, stream>>>(outf, A2B2);
}

// Round 7
// 783.319 us; speedup vs baseline: 1.0959x; 1.0959x over previous
//
#include <hip/hip_runtime.h>
#include <hip/hip_bf16.h>
#include <math.h>

#define BB 16
#define CC 128
#define LL 16384
#define SS 128
#define LK 4096
#define NHEAD 8
#define DH 16

typedef __attribute__((ext_vector_type(8))) short short8;
typedef __attribute__((ext_vector_type(4))) float f32x4;

__device__ __forceinline__ float gelu_f(float x) {
    return 0.5f * x * (1.0f + erff(x * 0.70710678118654752f));
}

__device__ __forceinline__ ushort f2bf(float f) {
    __hip_bfloat16 h = __float2bfloat16(f);
    return *(ushort*)&h;
}
__device__ __forceinline__ float bf2f(ushort u) {
    union { unsigned int i; float f; } x; x.i = ((unsigned int)u) << 16; return x.f;
}

// Reduce s1,s2 across the block; result valid in thread 0.
__device__ __forceinline__ void block_reduce2(float& s1, float& s2) {
    #pragma unroll
    for (int off = 32; off; off >>= 1) {
        s1 += __shfl_down(s1, off);
        s2 += __shfl_down(s2, off);
    }
    __shared__ float red[2][4];
    int wid = threadIdx.x >> 6, lid = threadIdx.x & 63;
    if (lid == 0) { red[0][wid] = s1; red[1][wid] = s2; }
    __syncthreads();
    if (threadIdx.x == 0) {
        int nw = blockDim.x >> 6;
        float a = 0.f, b = 0.f;
        for (int i = 0; i < nw; i++) { a += red[0][i]; b += red[1][i]; }
        s1 = a; s2 = b;
    }
}

// ---------------------------------------------------------------------------
// K_dw: depthwise 3x3, all 3 branches, fused stats. Round-5 structure
// (32-ch blocks, grid 8192, [b][cg4][p][c32] output) with NEW epilogue:
// bf16 results are ow-pair-packed into an LDS tile (reusing xs; stride 33
// dwords = bank-conflict-free both phases), then stored cooperatively as
// contiguous float4 chunks (1KB/wave). Scattered 2B stores: 32 -> 4/thread.
__global__ __launch_bounds__(256) void k_dw(const float* __restrict__ x,
        const float* __restrict__ dw_w,
        ushort* __restrict__ dwq, ushort* __restrict__ dwk, ushort* __restrict__ dwv,
        float* __restrict__ dwstats) {
    int bx = blockIdx.x;
    int cg = bx & 3;
    int oh = (bx >> 2) & 127;
    int b  = bx >> 9;
    __shared__ float xs[3][32][132];   // 50.7 KB; reused for transpose tiles
    int tid = threadIdx.x;
    int cl  = tid >> 3;        // channel-local 0..31
    int owg = tid & 7;
    int ow0 = owg * 16;
    int c   = cg * 32 + cl;
    bool do_kv = ((oh & 1) == 0);

    // weights into registers (8 lanes share c -> broadcast loads)
    float wq[9], wk[9], wv[9];
    const float* wp = dw_w + (size_t)c * 9;
    #pragma unroll
    for (int t = 0; t < 9; t++) wq[t] = wp[t];
    #pragma unroll
    for (int t = 0; t < 9; t++) wk[t] = wp[(size_t)CC * 9 + t];
    #pragma unroll
    for (int t = 0; t < 9; t++) wv[t] = wp[(size_t)2 * CC * 9 + t];

    // stage 3 input rows (32 ch x 128 floats); zero OOB rows
    for (int i = tid; i < 3 * 32 * 32; i += 256) {
        int r = i >> 10;
        int rem = i & 1023;
        int ch = rem >> 5;
        int f4 = rem & 31;
        int ih = oh - 1 + r;
        float4 v = make_float4(0.f, 0.f, 0.f, 0.f);
        if (ih >= 0 && ih < 128)
            v = *(const float4*)(x + ((size_t)b * CC + cg * 32 + ch) * (size_t)LL + ih * SS + f4 * 4);
        *(float4*)&xs[r][ch][f4 * 4] = v;
    }
    if (tid < 96) {
        int r = tid >> 5, ch = tid & 31;
        *(float4*)&xs[r][ch][128] = make_float4(0.f, 0.f, 0.f, 0.f);
    }
    __syncthreads();

    float aq[16], ak[8], av[8];
    #pragma unroll
    for (int j = 0; j < 16; j++) aq[j] = 0.f;
    #pragma unroll
    for (int j = 0; j < 8; j++) { ak[j] = 0.f; av[j] = 0.f; }

    #pragma unroll
    for (int r = 0; r < 3; r++) {
        const float* row = &xs[r][cl][0];
        float g[18];
        g[0] = owg ? row[ow0 - 1] : 0.f;
        float4 v0 = *(const float4*)&row[ow0];
        float4 v1 = *(const float4*)&row[ow0 + 4];
        float4 v2 = *(const float4*)&row[ow0 + 8];
        float4 v3 = *(const float4*)&row[ow0 + 12];
        g[1] = v0.x;  g[2] = v0.y;  g[3] = v0.z;  g[4] = v0.w;
        g[5] = v1.x;  g[6] = v1.y;  g[7] = v1.z;  g[8] = v1.w;
        g[9] = v2.x;  g[10] = v2.y; g[11] = v2.z; g[12] = v2.w;
        g[13] = v3.x; g[14] = v3.y; g[15] = v3.z; g[16] = v3.w;
        g[17] = row[ow0 + 16];
        float w0 = wq[3 * r], w1 = wq[3 * r + 1], w2 = wq[3 * r + 2];
        #pragma unroll
        for (int j = 0; j < 16; j++)
            aq[j] += w0 * g[j] + w1 * g[j + 1] + w2 * g[j + 2];
        if (do_kv) {
            float k0 = wk[3 * r], k1 = wk[3 * r + 1], k2 = wk[3 * r + 2];
            float x0 = wv[3 * r], x1 = wv[3 * r + 1], x2 = wv[3 * r + 2];
            #pragma unroll
            for (int j = 0; j < 8; j++) {
                ak[j] += k0 * g[2 * j] + k1 * g[2 * j + 1] + k2 * g[2 * j + 2];
                av[j] += x0 * g[2 * j] + x1 * g[2 * j + 1] + x2 * g[2 * j + 2];
            }
        }
    }

    // bf16 rounding + fused stats (sum over rounded values, as before)
    ushort qb[16], kb16[8], vb16[8];
    {
        float s1 = 0.f, s2 = 0.f;
        #pragma unroll
        for (int j = 0; j < 16; j++) {
            qb[j] = f2bf(aq[j]);
            float fv = bf2f(qb[j]);
            s1 += fv; s2 += fv * fv;
        }
        #pragma unroll
        for (int m = 1; m <= 4; m <<= 1) {
            s1 += __shfl_xor(s1, m);
            s2 += __shfl_xor(s2, m);
        }
        if (owg == 0) {
            atomicAdd(&dwstats[(size_t)c * 2 + 0], s1);
            atomicAdd(&dwstats[(size_t)c * 2 + 1], s2);
        }
    }
    if (do_kv) {
        float t1 = 0.f, t2 = 0.f, u1 = 0.f, u2 = 0.f;
        #pragma unroll
        for (int j = 0; j < 8; j++) {
            kb16[j] = f2bf(ak[j]);
            float fk = bf2f(kb16[j]);
            t1 += fk; t2 += fk * fk;
            vb16[j] = f2bf(av[j]);
            float fv = bf2f(vb16[j]);
            u1 += fv; u2 += fv * fv;
        }
        #pragma unroll
        for (int m = 1; m <= 4; m <<= 1) {
            t1 += __shfl_xor(t1, m); t2 += __shfl_xor(t2, m);
            u1 += __shfl_xor(u1, m); u2 += __shfl_xor(u2, m);
        }
        if (owg == 0) {
            atomicAdd(&dwstats[((size_t)CC + c) * 2 + 0], t1);
            atomicAdd(&dwstats[((size_t)CC + c) * 2 + 1], t2);
            atomicAdd(&dwstats[((size_t)2 * CC + c) * 2 + 0], u1);
            atomicAdd(&dwstats[((size_t)2 * CC + c) * 2 + 1], u2);
        }
    }

    // ---- LDS transpose (ow-pair packed dwords) + coalesced stores ----
    __syncthreads();    // all xs reads done; reuse the buffer
    unsigned int* qt = (unsigned int*)&xs[0][0][0];   // [64][33]
    unsigned int* kt = qt + 64 * 33;                  // [32][33]
    unsigned int* vt = kt + 32 * 33;                  // [32][33]
    #pragma unroll
    for (int jp = 0; jp < 8; jp++)
        qt[(owg * 8 + jp) * 33 + cl] = (unsigned int)qb[2 * jp] | ((unsigned int)qb[2 * jp + 1] << 16);
    if (do_kv) {
        #pragma unroll
        for (int jp = 0; jp < 4; jp++) {
            kt[(owg * 4 + jp) * 33 + cl] = (unsigned int)kb16[2 * jp] | ((unsigned int)kb16[2 * jp + 1] << 16);
            vt[(owg * 4 + jp) * 33 + cl] = (unsigned int)vb16[2 * jp] | ((unsigned int)vb16[2 * jp + 1] << 16);
        }
    }
    __syncthreads();
    // q: 512 chunks of 16B (128 p x 4 c8); contiguous 1KB per wave
    {
        ushort* qrow = dwq + (((size_t)b * 4 + cg) * LL + (size_t)oh * 128) * 32;
        #pragma unroll
        for (int cc = 0; cc < 2; cc++) {
            int i = tid + cc * 256;
            int p = i >> 2, c8 = (i & 3) * 8;
            int half = (p & 1) * 16;
            const unsigned int* src = qt + (p >> 1) * 33 + c8;
            union { ushort u[8]; float4 v; } pk;
            #pragma unroll
            for (int t2 = 0; t2 < 8; t2++) pk.u[t2] = (ushort)(src[t2] >> half);
            *(float4*)(qrow + (size_t)p * 32 + c8) = pk.v;
        }
    }
    if (do_kv) {
        int ohp = oh >> 1;
        size_t kvoff = (((size_t)b * 4 + cg) * LK + (size_t)ohp * 64) * 32;
        int p = tid >> 2, c8 = (tid & 3) * 8;
        int half = (p & 1) * 16;
        {
            const unsigned int* src = kt + (p >> 1) * 33 + c8;
            union { ushort u[8]; float4 v; } pk;
            #pragma unroll
            for (int t2 = 0; t2 < 8; t2++) pk.u[t2] = (ushort)(src[t2] >> half);
            *(float4*)(dwk + kvoff + (size_t)p * 32 + c8) = pk.v;
        }
        {
            const unsigned int* src = vt + (p >> 1) * 33 + c8;
            union { ushort u[8]; float4 v; } pk;
            #pragma unroll
            for (int t2 = 0; t2 < 8; t2++) pk.u[t2] = (ushort)(src[t2] >> half);
            *(float4*)(dwv + kvoff + (size_t)p * 32 + c8) = pk.v;
        }
    }
}

// ---------------------------------------------------------------------------
// Fold BN2d into pointwise: effWb[br][o][c] bf16, effB[br][o] fp32.
__global__ void k_finalize_dw(const float* __restrict__ stats, const float* __restrict__ pw_w,
                              const float* __restrict__ pw_b, const float* __restrict__ bn2_g,
                              const float* __restrict__ bn2_b,
                              ushort* __restrict__ effWb, float* __restrict__ effB) {
    int br = blockIdx.x >> 7;
    int o  = blockIdx.x & 127;
    int c  = threadIdx.x;
    float N = (br == 0) ? 262144.f : 65536.f;
    float s1 = stats[(br * CC + c) * 2 + 0];
    float s2 = stats[(br * CC + c) * 2 + 1];
    float m = s1 / N;
    float v = s2 / N - m * m;
    float sc = rsqrtf(v + 1e-5f);
    float A  = bn2_g[br * CC + c] * sc;
    float Bc = bn2_b[br * CC + c] - m * A;
    float w  = pw_w[((size_t)br * CC + o) * CC + c];
    effWb[((size_t)br * CC + o) * CC + c] = f2bf(w * A);
    float pb = w * Bc, dummy = 0.f;
    block_reduce2(pb, dummy);
    if (threadIdx.x == 0) effB[br * CC + o] = pw_b[br * CC + o] + pb;
}

// ---------------------------------------------------------------------------
// GEMM for k/v branches. B (effWb) staged in LDS; A fragments direct from
// global. Wave w owns rows w*16 and w*16+64 -> contiguous 64-row phase bands.
__global__ __launch_bounds__(256, 3) void k_gemm_kv(const ushort* __restrict__ dwk,
        const ushort* __restrict__ dwv, const ushort* __restrict__ effWb,
        const float* __restrict__ effB, float* __restrict__ kbuf, float* __restrict__ vbuf) {
    __shared__ __align__(16) char raw[34816];   // Bs [128][136] shorts; Sf [64][132] f32
    short* Bs = (short*)raw;
    float* Sf = (float*)raw;
    int bx = blockIdx.x;
    int brv = bx >> 9;
    int b = (bx >> 5) & 15;
    int p0 = (bx & 31) * 128;
    const ushort* dw = brv ? dwv : dwk;
    const ushort* Wg = effWb + (size_t)(1 + brv) * CC * CC;
    int tid = threadIdx.x;
    for (int i = tid; i < 2048; i += 256) {
        int row = i >> 4; int f4 = i & 15;
        float4 v = *(const float4*)(Wg + (size_t)row * 128 + f4 * 8);
        *(float4*)&Bs[row * 136 + f4 * 8] = v;
    }
    __syncthreads();
    int w = tid >> 6, l = tid & 63;
    int m0 = w * 16;
    int la = l & 15, lb = l >> 4;
    f32x4 acc[2][8];
    #pragma unroll
    for (int i = 0; i < 2; i++)
        #pragma unroll
        for (int j = 0; j < 8; j++) acc[i][j] = (f32x4){0.f, 0.f, 0.f, 0.f};
    #pragma unroll
    for (int kt = 0; kt < 4; kt++) {
        short8 a0 = *(const short8*)(dw + (((size_t)b * 4 + kt) * LK + p0 + m0 + la) * 32 + lb * 8);
        short8 a1 = *(const short8*)(dw + (((size_t)b * 4 + kt) * LK + p0 + m0 + 64 + la) * 32 + lb * 8);
        int kb = kt * 32 + lb * 8;
        #pragma unroll
        for (int nt = 0; nt < 8; nt++) {
            short8 bf = *(const short8*)&Bs[(nt * 16 + la) * 136 + kb];
            acc[0][nt] = __builtin_amdgcn_mfma_f32_16x16x32_bf16(a0, bf, acc[0][nt], 0, 0, 0);
            acc[1][nt] = __builtin_amdgcn_mfma_f32_16x16x32_bf16(a1, bf, acc[1][nt], 0, 0, 0);
        }
    }
    float bias[8];
    #pragma unroll
    for (int nt = 0; nt < 8; nt++) bias[nt] = effB[(1 + brv) * CC + nt * 16 + la];
    float* outb = (brv ? vbuf : kbuf) + ((size_t)b * LK + p0) * CC;
    #pragma unroll
    for (int t = 0; t < 2; t++) {
        __syncthreads();   // t=0: Bs dead; t=1: prior Sf reads done
        #pragma unroll
        for (int nt = 0; nt < 8; nt++)
            #pragma unroll
            for (int i = 0; i < 4; i++) {
                float vv = acc[t][nt][i] + bias[nt];
                Sf[(m0 + lb * 4 + i) * 132 + nt * 16 + la] = gelu_f(vv);
            }
        __syncthreads();
        for (int i = tid; i < 2048; i += 256) {
            int r = i >> 5; int c4 = i & 31;
            *(float4*)(outb + (size_t)(t * 64 + r) * CC + c4 * 4) = *(const float4*)&Sf[r * 132 + c4 * 4];
        }
    }
}

// ---------------------------------------------------------------------------
// kv accumulation (softmax over sequence): unchanged.
__global__ void k_kv_accum(const float* __restrict__ k_buf, const float* __restrict__ v_buf,
                           float* __restrict__ kv_un, float* __restrict__ ssum) {
    int bx = blockIdx.x;
    int b = bx >> 5;
    int h = (bx >> 2) & 7;
    int sl = bx & 3;
    int n0 = sl * 1024;
    __shared__ float kch[64][16];
    __shared__ float vch[64][16];
    int tid = threadIdx.x;
    int d = tid >> 4, e = tid & 15;
    float acc = 0.f, ss = 0.f;
    for (int ch = 0; ch < 16; ch++) {
        int base = n0 + ch * 64;
        {
            int rr = tid >> 2, c4 = (tid & 3) * 4;
            const float* kp = k_buf + ((size_t)b * LK + base + rr) * CC + h * DH + c4;
            const float* vp = v_buf + ((size_t)b * LK + base + rr) * CC + h * DH + c4;
            float4 kf = *(const float4*)kp;
            float4 vf = *(const float4*)vp;
            kch[rr][c4+0] = __expf(kf.x); kch[rr][c4+1] = __expf(kf.y);
            kch[rr][c4+2] = __expf(kf.z); kch[rr][c4+3] = __expf(kf.w);
            vch[rr][c4+0] = vf.x; vch[rr][c4+1] = vf.y;
            vch[rr][c4+2] = vf.z; vch[rr][c4+3] = vf.w;
        }
        __syncthreads();
        #pragma unroll 8
        for (int rr = 0; rr < 64; rr++) {
            float ek = kch[rr][d];
            acc += ek * vch[rr][e];
            ss += ek;
        }
        __syncthreads();
    }
    atomicAdd(&kv_un[(((size_t)b * NHEAD + h) * DH + d) * DH + e], acc);
    if (e == 0) atomicAdd(&ssum[((size_t)b * NHEAD + h) * DH + d], ss);
}

__global__ void k_kv_div(const float* __restrict__ kv_un, const float* __restrict__ ssum,
                         float* __restrict__ kv) {
    int i = blockIdx.x * 256 + threadIdx.x;
    kv[i] = kv_un[i] / ssum[i >> 4];
}

// ---------------------------------------------------------------------------
// GEMM for q branch + gelu + softmax(dh) + attention + residual. grid 2048.
// B staged in LDS, A direct-global, contiguous 2-phase epilogue.
__global__ __launch_bounds__(256, 3) void k_gemm_q(const ushort* __restrict__ dwq,
        const ushort* __restrict__ effWb, const float* __restrict__ effB,
        const float* __restrict__ kvb, const float* __restrict__ add_w,
        const float* __restrict__ x, float* __restrict__ y1) {
    __shared__ __align__(16) char raw[34816];   // Bs [128][136] shorts; Sf [64][133] f32
    short* Bs = (short*)raw;
    float* Sf = (float*)raw;
    __shared__ float kvs[2048];
    int bx = blockIdx.x;
    int b = bx >> 7;
    int p0 = (bx & 127) * 128;
    int tid = threadIdx.x;
    for (int i = tid; i < 512; i += 256)
        *(float4*)&kvs[i * 4] = *(const float4*)(kvb + (size_t)b * 2048 + i * 4);
    for (int i = tid; i < 2048; i += 256) {
        int row = i >> 4; int f4 = i & 15;
        float4 v = *(const float4*)(effWb + (size_t)row * 128 + f4 * 8);
        *(float4*)&Bs[row * 136 + f4 * 8] = v;
    }
    __syncthreads();
    int w = tid >> 6, l = tid & 63;
    int m0 = w * 16;
    int la = l & 15, lb = l >> 4;
    f32x4 acc[2][8];
    #pragma unroll
    for (int i = 0; i < 2; i++)
        #pragma unroll
        for (int j = 0; j < 8; j++) acc[i][j] = (f32x4){0.f, 0.f, 0.f, 0.f};
    #pragma unroll
    for (int kt = 0; kt < 4; kt++) {
        short8 a0 = *(const short8*)(dwq + (((size_t)b * 4 + kt) * LL + p0 + m0 + la) * 32 + lb * 8);
        short8 a1 = *(const short8*)(dwq + (((size_t)b * 4 + kt) * LL + p0 + m0 + 64 + la) * 32 + lb * 8);
        int kb = kt * 32 + lb * 8;
        #pragma unroll
        for (int nt = 0; nt < 8; nt++) {
            short8 bf = *(const short8*)&Bs[(nt * 16 + la) * 136 + kb];
            acc[0][nt] = __builtin_amdgcn_mfma_f32_16x16x32_bf16(a0, bf, acc[0][nt], 0, 0, 0);
            acc[1][nt] = __builtin_amdgcn_mfma_f32_16x16x32_bf16(a1, bf, acc[1][nt], 0, 0, 0);
        }
    }
    float bias[8];
    #pragma unroll
    for (int nt = 0; nt < 8; nt++) bias[nt] = effB[nt * 16 + la];
    float wa0 = add_w[0], wa1 = add_w[1];
    float r0 = fmaxf(wa0, 0.f), r1 = fmaxf(wa1, 0.f);
    float inv = 1.f / (r0 + r1 + 1e-12f);
    float wn0 = r0 * inv, wn1 = r1 * inv;
    #pragma unroll
    for (int t = 0; t < 2; t++) {
        __syncthreads();   // t=0: Bs dead; t=1: prior Sf reads done
        #pragma unroll
        for (int nt = 0; nt < 8; nt++)
            #pragma unroll
            for (int i = 0; i < 4; i++) {
                float vv = acc[t][nt][i] + bias[nt];
                Sf[(m0 + lb * 4 + i) * 133 + nt * 16 + la] = gelu_f(vv);
            }
        __syncthreads();
        // epilogue on the contiguous 64 rows of this phase
        int r64 = tid & 63;
        int hg = tid >> 6;           // wave id -> h wave-uniform (kvs broadcast)
        int pact = t * 64 + r64;
        const float* xb = x + (size_t)b * CC * (size_t)LL + p0 + pact;
        float* yb = y1 + (size_t)b * CC * (size_t)LL + p0 + pact;
        #pragma unroll
        for (int hh = 0; hh < 2; hh++) {
            int h = hg * 2 + hh;
            float sv[16];
            float mx = -1e30f;
            #pragma unroll
            for (int d = 0; d < 16; d++) { sv[d] = Sf[r64 * 133 + h * 16 + d]; mx = fmaxf(mx, sv[d]); }
            float s = 0.f;
            #pragma unroll
            for (int d = 0; d < 16; d++) { sv[d] = __expf(sv[d] - mx); s += sv[d]; }
            float is = 1.f / s;
            #pragma unroll
            for (int e = 0; e < 16; e++) {
                float att = 0.f;
                #pragma unroll
                for (int d = 0; d < 16; d++) att += sv[d] * kvs[(h * 16 + d) * 16 + e];
                int c = h * 16 + e;
                yb[(size_t)c * LL] = wn0 * att * is + wn1 * xb[(size_t)c * LL];
            }
        }
    }
}

// ---------------------------------------------------------------------------
// Per-channel sum/sumsq over [B][C][L]. grid 4096.
__global__ void k_chan_stats(const float* __restrict__ buf, float* __restrict__ stats) {
    int c = blockIdx.x >> 5;
    int s = blockIdx.x & 31;
    int b = s >> 1;
    int p0 = (s & 1) << 13;
    const float* src = buf + (size_t)b * (CC * (size_t)LL) + (size_t)c * LL + p0;
    float s1 = 0.f, s2 = 0.f;
    for (int i = threadIdx.x * 4; i < 8192; i += 1024) {
        float4 v = *(const float4*)(src + i);
        s1 += v.x + v.y + v.z + v.w;
        s2 += v.x * v.x + v.y * v.y + v.z * v.z + v.w * v.w;
    }
    block_reduce2(s1, s2);
    if (threadIdx.x == 0) {
        atomicAdd(&stats[c * 2 + 0], s1);
        atomicAdd(&stats[c * 2 + 1], s2);
    }
}

// ---------------------------------------------------------------------------
__global__ void k_fin1(const float* __restrict__ stats1, const float* __restrict__ bn1_g,
                       const float* __restrict__ bn1_b, const float* __restrict__ W1,
                       const float* __restrict__ b1, const float* __restrict__ W2,
                       float* __restrict__ A1B1, float* __restrict__ effW1,
                       float* __restrict__ effb1, float* __restrict__ W2T) {
    int t = threadIdx.x;
    const float N = 262144.f;
    float m = stats1[t * 2] / N;
    float v = stats1[t * 2 + 1] / N - m * m;
    float sc = rsqrtf(v + 1e-5f);
    float A = bn1_g[t] * sc;
    float Bc = bn1_b[t] - m * A;
    A1B1[t] = A; A1B1[128 + t] = Bc;
    __shared__ float Bs[128];
    Bs[t] = Bc;
    for (int j = 0; j < 32; j++) effW1[t * 32 + j] = W1[t * 32 + j] * A;
    for (int j = 0; j < 32; j++) W2T[t * 32 + j] = W2[j * 128 + t];
    __syncthreads();
    if (t < 32) {
        float s = b1[t];
        for (int c = 0; c < 128; c++) s += W1[c * 32 + t] * Bs[c];
        effb1[t] = s;
    }
}

// ---------------------------------------------------------------------------
// FFN1: f1[b,p,j] = gelu(sum_c effW1[c][j]*y1[b,c,p] + effb1[j]); LDS weights.
__global__ __launch_bounds__(256) void k_ffn1(const float* __restrict__ y1,
        const float* __restrict__ effW1, const float* __restrict__ effb1,
        float* __restrict__ f1) {
    __shared__ float wl[4096];
    __shared__ float bl[32];
    int tid = threadIdx.x;
    for (int i = tid; i < 4096; i += 256) wl[i] = effW1[i];
    if (tid < 32) bl[tid] = effb1[tid];
    __syncthreads();
    int gp = blockIdx.x * 256 + tid;
    int b = gp >> 14, p = gp & 16383;
    const float* col = y1 + (size_t)b * (CC * (size_t)LL) + p;
    float acc[32];
    #pragma unroll
    for (int j = 0; j < 32; j++) acc[j] = bl[j];
    for (int c = 0; c < CC; c++) {
        float v = col[(size_t)c * LL];
        const float4* w4 = (const float4*)&wl[c * 32];
        #pragma unroll
        for (int i = 0; i < 8; i++) {
            float4 w = w4[i];
            acc[4*i+0] += w.x * v; acc[4*i+1] += w.y * v;
            acc[4*i+2] += w.z * v; acc[4*i+3] += w.w * v;
        }
    }
    float4* dst = (float4*)(f1 + (size_t)gp * 32);
    #pragma unroll
    for (int i = 0; i < 8; i++) {
        float4 o4;
        o4.x = gelu_f(acc[4*i+0]); o4.y = gelu_f(acc[4*i+1]);
        o4.z = gelu_f(acc[4*i+2]); o4.w = gelu_f(acc[4*i+3]);
        dst[i] = o4;
    }
}

// ---------------------------------------------------------------------------
// FFN2: f2 = gelu(f1@W2+b2); out = wn0*f2 + wn1*(y1*A1+B1); LDS weights.
__global__ __launch_bounds__(256) void k_ffn2(const float* __restrict__ f1,
        const float* __restrict__ W2T, const float* __restrict__ b2,
        const float* __restrict__ y1, const float* __restrict__ A1B1,
        const float* __restrict__ ffn_add_w, float* __restrict__ outb) {
    __shared__ float wl[4096];
    __shared__ float b2l[128];
    __shared__ float abl[256];
    int tid = threadIdx.x;
    for (int i = tid; i < 4096; i += 256) wl[i] = W2T[i];
    if (tid < 128) b2l[tid] = b2[tid];
    if (tid >= 128) abl[tid - 128] = A1B1[tid - 128];
    if (tid < 128) abl[128 + tid] = A1B1[128 + tid];
    __syncthreads();
    int gp = blockIdx.x * 256 + tid;
    int b = gp >> 14, p = gp & 16383;
    float f[32];
    {
        const float4* src = (const float4*)(f1 + (size_t)gp * 32);
        #pragma unroll
        for (int i = 0; i < 8; i++) {
            float4 v = src[i];
            f[4*i+0] = v.x; f[4*i+1] = v.y; f[4*i+2] = v.z; f[4*i+3] = v.w;
        }
    }
    float wa0 = ffn_add_w[0], wa1 = ffn_add_w[1];
    float r0 = fmaxf(wa0, 0.f), r1 = fmaxf(wa1, 0.f);
    float inv = 1.f / (r0 + r1 + 1e-12f);
    float wn0 = r0 * inv, wn1 = r1 * inv;
    const float* ycol = y1 + (size_t)b * (CC * (size_t)LL) + p;
    float* ocol = outb + (size_t)b * (CC * (size_t)LL) + p;
    for (int c = 0; c < CC; c++) {
        const float4* w4 = (const float4*)&wl[c * 32];
        float a = b2l[c];
        #pragma unroll
        for (int i = 0; i < 8; i++) {
            float4 w = w4[i];
            a += w.x * f[4*i+0] + w.y * f[4*i+1] + w.z * f[4*i+2] + w.w * f[4*i+3];
        }
        float f2 = gelu_f(a);
        float attv = ycol[(size_t)c * LL] * abl[c] + abl[128 + c];
        ocol[(size_t)c * LL] = wn0 * f2 + wn1 * attv;
    }
}

__global__ void k_fin2(const float* __restrict__ stats2, const float* __restrict__ g,
                       const float* __restrict__ bb, float* __restrict__ A2B2) {
    int t = threadIdx.x;
    const float N = 262144.f;
    float m = stats2[t * 2] / N;
    float v = stats2[t * 2 + 1] / N - m * m;
    float sc = rsqrtf(v + 1e-5f);
    float A = g[t] * sc;
    A2B2[t] = A;
    A2B2[128 + t] = bb[t] - m * A;
}

__global__ void k_norm(float* __restrict__ out, const float* __restrict__ A2B2) {
    size_t i = ((size_t)blockIdx.x * 256 + threadIdx.x) * 4;
    int c = (int)((i >> 14) & 127);
    float A = A2B2[c], Bc = A2B2[128 + c];
    float4 v = *(float4*)(out + i);
    v.x = v.x * A + Bc; v.y = v.y * A + Bc; v.z = v.z * A + Bc; v.w = v.w * A + Bc;
    *(float4*)(out + i) = v;
}

// ---------------------------------------------------------------------------
extern "C" void kernel_launch(void* const* d_in, const int* in_sizes, int n_in,
                              void* d_out, int out_size, void* d_ws, size_t ws_size,
                              hipStream_t stream) {
    const float* x        = (const float*)d_in[0];
    const float* dw_w     = (const float*)d_in[1];
    const float* bn2_g    = (const float*)d_in[2];
    const float* bn2_b    = (const float*)d_in[3];
    const float* pw_w     = (const float*)d_in[4];
    const float* pw_b     = (const float*)d_in[5];
    const float* add_w    = (const float*)d_in[6];
    const float* bn1_g    = (const float*)d_in[7];
    const float* bn1_b    = (const float*)d_in[8];
    const float* W1       = (const float*)d_in[9];
    const float* b1       = (const float*)d_in[10];
    const float* W2       = (const float*)d_in[11];
    const float* b2       = (const float*)d_in[12];
    const float* ffn_aw   = (const float*)d_in[13];
    const float* ffn_bn_g = (const float*)d_in[14];
    const float* ffn_bn_b = (const float*)d_in[15];

    float* w = (float*)d_ws;
    size_t off = 0;
    auto alloc = [&](size_t n) { float* p = w + off; off += n; return p; };
    // zero-init accumulator region (contiguous, single memset)
    float* dwstats = alloc(768);
    float* stats1  = alloc(256);
    float* stats2  = alloc(256);
    float* kv_un   = alloc(32768);
    float* ssum    = alloc(2048);
    size_t zero_bytes = off * sizeof(float);
    float* effWb_f = alloc(24576);   // 3*128*128 bf16
    float* effB    = alloc(384);
    float* kvb     = alloc(32768);
    float* A1B1    = alloc(256);
    float* effW1   = alloc(4096);
    float* effb1   = alloc(32);
    float* W2T     = alloc(4096);
    float* A2B2    = alloc(256);
    float* y1      = alloc((size_t)BB * CC * LL);
    float* kbuf    = alloc((size_t)BB * LK * CC);
    float* vbuf    = alloc((size_t)BB * LK * CC);
    float* dwq_f   = alloc((size_t)BB * LL * CC / 2);   // bf16
    float* dwk_f   = alloc((size_t)BB * LK * CC / 2);
    float* dwv_f   = alloc((size_t)BB * LK * CC / 2);
    float* f1      = kbuf;   // alias: kbuf dead after k_kv_accum
    (void)ws_size;

    ushort* effWb = (ushort*)effWb_f;
    ushort* dwq = (ushort*)dwq_f;
    ushort* dwk = (ushort*)dwk_f;
    ushort* dwv = (ushort*)dwv_f;
    float* outf = (float*)d_out;

    hipMemsetAsync(d_ws, 0, zero_bytes, stream);

    k_dw<<<8192, 256, 0, stream>>>(x, dw_w, dwq, dwk, dwv, dwstats);
    k_finalize_dw<<<384, 128, 0, stream>>>(dwstats, pw_w, pw_b, bn2_g, bn2_b, effWb, effB);
    k_gemm_kv<<<1024, 256, 0, stream>>>(dwk, dwv, effWb, effB, kbuf, vbuf);
    k_kv_accum<<<512, 256, 0, stream>>>(kbuf, vbuf, kv_un, ssum);
    k_kv_div<<<128, 256, 0, stream>>>(kv_un, ssum, kvb);
    k_gemm_q<<<2048, 256, 0, stream>>>(dwq, effWb, effB, kvb, add_w, x, y1);
    k_chan_stats<<<4096, 256, 0, stream>>>(y1, stats1);
    k_fin1<<<1, 128, 0, stream>>>(stats1, bn1_g, bn1_b, W1, b1, W2, A1B1, effW1, effb1, W2T);
    k_ffn1<<<1024, 256, 0, stream>>>(y1, effW1, effb1, f1);
    k_ffn2<<<1024, 256, 0, stream>>>(f1, W2T, b2, y1, A1B1, ffn_aw, outf);
    k_chan_stats<<<4096, 256, 0, stream>>>(outf, stats2);
    k_fin2<<<1, 128, 0, stream>>>(stats2, ffn_bn_g, ffn_bn_b, A2B2);
    k_norm<<<32768, 256, 0, stream>>>(outf, A2B2);
}